// Round 15
// baseline (189.135 us; speedup 1.0000x reference)
//
#include <hip/hip_runtime.h>
#include <math.h>

#define NUM_EMB 512
#define EDIM 64
#define BATCH 32
#define HW 4096
#define NROWS (BATCH * HW)        // 131072
#define NQ (NROWS * EDIM)         // 8388608

#define RPB 128                   // rows per block
#define KPP 128                   // k per pass
#define NPASS 4

// LDS layout in floats (17024 floats = 68096 B -> 2 blocks/CU, round-10 proven)
#define XOFF 0                    // x_t[c][r] : c*128 + r  (64 x 128) = 8192
#define EOFF 8192                 // e_t[c][k] : c*128 + k  (64 x 128) = 8192
                                  //   (post-loop overlay: CB [w][128] at EOFF,
                                  //    CK ints at EOFF+1024)
#define T2OFF 16384               // t2[512]
#define T1OFF 16896               // t1[128]  (post-combine overlay: KF ints)
#define SFLOATS 17024

typedef float f32x2 __attribute__((ext_vector_type(2)));
typedef float f32x4 __attribute__((ext_vector_type(4)));

// One packed fp32 FMA: acc.{lo,hi} += x2.{lo,hi} * e2.{lo,hi}, each component
// an exact IEEE rn fma -> preserves the per-k sequential ascending-c chain.
#define PKFMA(ACC, X2, E2) \
    asm("v_pk_fma_f32 %0, %1, %2, %0" : "+v"(ACC) : "v"(X2), "v"(E2))

// numpy pairwise_sum for n=64 contiguous fp32 (tiny prep kernel only).
__device__ __forceinline__ float pairwise8_64(const float* v) {
    float r0 = v[0], r1 = v[1], r2 = v[2], r3 = v[3];
    float r4 = v[4], r5 = v[5], r6 = v[6], r7 = v[7];
#pragma unroll
    for (int i = 8; i < 64; i += 8) {
        r0 = __fadd_rn(r0, v[i + 0]);
        r1 = __fadd_rn(r1, v[i + 1]);
        r2 = __fadd_rn(r2, v[i + 2]);
        r3 = __fadd_rn(r3, v[i + 3]);
        r4 = __fadd_rn(r4, v[i + 4]);
        r5 = __fadd_rn(r5, v[i + 5]);
        r6 = __fadd_rn(r6, v[i + 6]);
        r7 = __fadd_rn(r7, v[i + 7]);
    }
    return __fadd_rn(__fadd_rn(__fadd_rn(r0, r1), __fadd_rn(r2, r3)),
                     __fadd_rn(__fadd_rn(r4, r5), __fadd_rn(r6, r7)));
}

// ws_f layout: [0] = loss sum accumulator, [8..8+511] = t2[k] = ||emb_k||^2
__global__ void vq_prep(const float* __restrict__ emb, float* __restrict__ ws_f) {
    int k = blockIdx.x * blockDim.x + threadIdx.x;
    if (k == 0) ws_f[0] = 0.0f;
    if (k < NUM_EMB) {
        const float* e = emb + k * EDIM;
        float sq[EDIM];
#pragma unroll
        for (int c = 0; c < EDIM; ++c) sq[c] = __fmul_rn(e[c], e[c]);
        ws_f[8 + k] = pairwise8_64(sq);
    }
}

// Round-15: v_pk_fma_f32 inner loop. 512 thr = 8 waves; wave w owns k-slice
// [p*128 + w*16, +16) -> e_t reads wave-uniform (broadcast, free); lane owns
// rows {2*lane, 2*lane+1} -> x read = 1 ds_read_b64/c (2-way alias, free).
// acc = 2 rows x 8 k-pairs of f32x2 (32 VGPR) -> ~75 live, no spill pressure.
// Per (row,k): ONE ascending-c chain (pk components independent) -> bit-exact.
__global__ __launch_bounds__(512, 4) void vq_main(const float* __restrict__ z,
                                                  const float* __restrict__ emb,
                                                  float* __restrict__ out,
                                                  float* __restrict__ ws_f) {
    __shared__ float S[SFLOATS];
    const int tid  = threadIdx.x;
    const int lane = tid & 63;
    const int w    = tid >> 6;        // wave id 0..7
    const int bb   = blockIdx.x;      // 1024 blocks
    const int b    = bb >> 5;         // image
    const int hwb  = (bb & 31) << 7;  // 128-row base within image

    const float* zb = z + (size_t)b * (EDIM * HW) + hwb;

    // ---- stage x_t[c][r] + t2 ----
    {
        const int r = tid & 127, cq = tid >> 7;   // cq 0..3 -> 16 c each
#pragma unroll
        for (int j = 0; j < 16; ++j) {
            const int c = cq * 16 + j;
            S[XOFF + c * RPB + r] = zb[(size_t)c * HW + r];  // coalesced
        }
    }
    S[T2OFF + tid] = ws_f[8 + tid];
    __syncthreads();

    // ---- t1 per row: numpy pairwise-8, ascending c ----
    if (tid < RPB) {
        const float* xr = &S[XOFF + tid];   // stride RPB per c
        float q0 = __fmul_rn(xr[0 * RPB], xr[0 * RPB]);
        float q1 = __fmul_rn(xr[1 * RPB], xr[1 * RPB]);
        float q2 = __fmul_rn(xr[2 * RPB], xr[2 * RPB]);
        float q3 = __fmul_rn(xr[3 * RPB], xr[3 * RPB]);
        float q4 = __fmul_rn(xr[4 * RPB], xr[4 * RPB]);
        float q5 = __fmul_rn(xr[5 * RPB], xr[5 * RPB]);
        float q6 = __fmul_rn(xr[6 * RPB], xr[6 * RPB]);
        float q7 = __fmul_rn(xr[7 * RPB], xr[7 * RPB]);
#pragma unroll
        for (int m = 1; m < 8; ++m) {
            float v0 = xr[(8 * m + 0) * RPB], v1 = xr[(8 * m + 1) * RPB];
            float v2 = xr[(8 * m + 2) * RPB], v3 = xr[(8 * m + 3) * RPB];
            float v4 = xr[(8 * m + 4) * RPB], v5 = xr[(8 * m + 5) * RPB];
            float v6 = xr[(8 * m + 6) * RPB], v7 = xr[(8 * m + 7) * RPB];
            q0 = __fadd_rn(q0, __fmul_rn(v0, v0));
            q1 = __fadd_rn(q1, __fmul_rn(v1, v1));
            q2 = __fadd_rn(q2, __fmul_rn(v2, v2));
            q3 = __fadd_rn(q3, __fmul_rn(v3, v3));
            q4 = __fadd_rn(q4, __fmul_rn(v4, v4));
            q5 = __fadd_rn(q5, __fmul_rn(v5, v5));
            q6 = __fadd_rn(q6, __fmul_rn(v6, v6));
            q7 = __fadd_rn(q7, __fmul_rn(v7, v7));
        }
        S[T1OFF + tid] = __fadd_rn(__fadd_rn(__fadd_rn(q0, q1), __fadd_rn(q2, q3)),
                                   __fadd_rn(__fadd_rn(q4, q5), __fadd_rn(q6, q7)));
    }
    __syncthreads();

    const float t1lo = S[T1OFF + 2 * lane];       // row 2*lane
    const float t1hi = S[T1OFF + 2 * lane + 1];   // row 2*lane+1

    float best0 = INFINITY, best1 = INFINITY;
    int   bk0 = 0, bk1 = 0;
    const int kb = w * 16;   // this wave's k offset within a pass

    // ---- 4 passes of 128 k ----
#pragma unroll 1
    for (int p = 0; p < NPASS; ++p) {
        // stage e_t[c][k]; lanes write consecutive k -> conflict-free
        {
            const int k = tid & 127, cq = tid >> 7;
            const f32x4* er = (const f32x4*)(emb + (size_t)(p * KPP + k) * EDIM);
#pragma unroll
            for (int j = 0; j < 4; ++j) {
                const f32x4 v = er[cq * 4 + j];
                const int c = cq * 16 + j * 4;
                S[EOFF + (c + 0) * KPP + k] = v.x;
                S[EOFF + (c + 1) * KPP + k] = v.y;
                S[EOFF + (c + 2) * KPP + k] = v.z;
                S[EOFF + (c + 3) * KPP + k] = v.w;
            }
        }
        __syncthreads();

        f32x2 a0[8], a1[8];
#pragma unroll
        for (int j = 0; j < 8; ++j) { a0[j] = (f32x2){0.f, 0.f}; a1[j] = (f32x2){0.f, 0.f}; }

#pragma unroll 4
        for (int c = 0; c < 64; ++c) {
            // x: rows (2*lane, 2*lane+1) -> one b64, 2-way bank alias (free)
            const f32x2 xv = *(const f32x2*)&S[XOFF + c * RPB + 2 * lane];
            // e: wave-uniform addresses -> broadcast b128 (free)
            const f32x4 ea = *(const f32x4*)&S[EOFF + c * KPP + kb];
            const f32x4 eb = *(const f32x4*)&S[EOFF + c * KPP + kb + 4];
            const f32x4 ec = *(const f32x4*)&S[EOFF + c * KPP + kb + 8];
            const f32x4 ed = *(const f32x4*)&S[EOFF + c * KPP + kb + 12];
            const f32x2 e0 = __builtin_shufflevector(ea, ea, 0, 1);
            const f32x2 e1 = __builtin_shufflevector(ea, ea, 2, 3);
            const f32x2 e2 = __builtin_shufflevector(eb, eb, 0, 1);
            const f32x2 e3 = __builtin_shufflevector(eb, eb, 2, 3);
            const f32x2 e4 = __builtin_shufflevector(ec, ec, 0, 1);
            const f32x2 e5 = __builtin_shufflevector(ec, ec, 2, 3);
            const f32x2 e6 = __builtin_shufflevector(ed, ed, 0, 1);
            const f32x2 e7 = __builtin_shufflevector(ed, ed, 2, 3);
            const f32x2 x0 = __builtin_shufflevector(xv, xv, 0, 0);
            const f32x2 x1 = __builtin_shufflevector(xv, xv, 1, 1);
            PKFMA(a0[0], x0, e0); PKFMA(a0[1], x0, e1);
            PKFMA(a0[2], x0, e2); PKFMA(a0[3], x0, e3);
            PKFMA(a0[4], x0, e4); PKFMA(a0[5], x0, e5);
            PKFMA(a0[6], x0, e6); PKFMA(a0[7], x0, e7);
            PKFMA(a1[0], x1, e0); PKFMA(a1[1], x1, e1);
            PKFMA(a1[2], x1, e2); PKFMA(a1[3], x1, e3);
            PKFMA(a1[4], x1, e4); PKFMA(a1[5], x1, e5);
            PKFMA(a1[6], x1, e6); PKFMA(a1[7], x1, e7);
        }

        // finish: d = fl(fl(t1+t2) - fl(2*p)); k ascending (pair lo then hi)
#pragma unroll
        for (int j = 0; j < 8; ++j) {
            const int kg = p * KPP + kb + 2 * j;
            const float t2lo = S[T2OFF + kg];
            const float t2hi = S[T2OFF + kg + 1];
            float d;
            d = __fsub_rn(__fadd_rn(t1lo, t2lo), __fmul_rn(2.0f, a0[j].x));
            if (d < best0) { best0 = d; bk0 = kg; }
            d = __fsub_rn(__fadd_rn(t1lo, t2hi), __fmul_rn(2.0f, a0[j].y));
            if (d < best0) { best0 = d; bk0 = kg + 1; }
            d = __fsub_rn(__fadd_rn(t1hi, t2lo), __fmul_rn(2.0f, a1[j].x));
            if (d < best1) { best1 = d; bk1 = kg; }
            d = __fsub_rn(__fadd_rn(t1hi, t2hi), __fmul_rn(2.0f, a1[j].y));
            if (d < best1) { best1 = d; bk1 = kg + 1; }
        }
        __syncthreads();   // e_t consumed; safe to restage / overlay
    }

    // ---- combine across the 8 waves (CB/CK overlay e_t) ----
    S[EOFF + w * RPB + 2 * lane]     = best0;
    S[EOFF + w * RPB + 2 * lane + 1] = best1;
    ((int*)S)[EOFF + 1024 + w * RPB + 2 * lane]     = bk0;
    ((int*)S)[EOFF + 1024 + w * RPB + 2 * lane + 1] = bk1;
    __syncthreads();

    if (tid < RPB) {
        float B = INFINITY;
        int   K = 0;
        // lexicographic (d,k) min == numpy argmin lowest-index tie-break
#pragma unroll
        for (int q = 0; q < 8; ++q) {
            const float bq = S[EOFF + q * RPB + tid];
            const int   kq = ((int*)S)[EOFF + 1024 + q * RPB + tid];
            if (bq < B || (bq == B && kq < K)) { B = bq; K = kq; }
        }
        ((int*)S)[T1OFF + tid] = K;                       // KF (t1 dead)
        out[(size_t)NQ + 2 + bb * RPB + tid] = (float)K;  // idx as fp32
    }
    __syncthreads();

    // ---- epilogue: wave w writes c in [8w, 8w+8) for rows {lane, 64+lane} ----
    float s = 0.0f;
#pragma unroll
    for (int h = 0; h < 2; ++h) {
        const int rr = h * 64 + lane;
        const int K  = ((int*)S)[T1OFF + rr];
        const float* ebp = emb + (size_t)K * EDIM;
#pragma unroll
        for (int j = 0; j < 8; ++j) {
            const int c = w * 8 + j;
            const float x = S[XOFF + c * RPB + rr];
            const float f = __fsub_rn(ebp[c], x);
            out[((size_t)b * EDIM + c) * HW + hwb + rr] = __fadd_rn(x, f);
            s = __fmaf_rn(f, f, s);
        }
    }
#pragma unroll
    for (int off = 32; off > 0; off >>= 1) s += __shfl_down(s, off);
    if (lane == 0) atomicAdd(ws_f, s);
}

__global__ void vq_final(const float* __restrict__ ws_f, float* __restrict__ out) {
    float m = ws_f[0] * (1.0f / (float)NQ);   // 2^-23, exact scaling
    out[NQ + 0] = m;
    out[NQ + 1] = m;
}

extern "C" void kernel_launch(void* const* d_in, const int* in_sizes, int n_in,
                              void* d_out, int out_size, void* d_ws, size_t ws_size,
                              hipStream_t stream) {
    const float* z = (const float*)d_in[0];     // [32, 64, 64, 64] fp32
    const float* emb = (const float*)d_in[1];   // [512, 64] fp32
    float* out = (float*)d_out;
    float* ws_f = (float*)d_ws;

    hipLaunchKernelGGL(vq_prep, dim3(1), dim3(512), 0, stream, emb, ws_f);
    hipLaunchKernelGGL(vq_main, dim3(NROWS / RPB), dim3(512), 0, stream, z, emb, out, ws_f);
    hipLaunchKernelGGL(vq_final, dim3(1), dim3(1), 0, stream, ws_f, out);
}

// Round 16
// 142.533 us; speedup vs baseline: 1.3270x; 1.3270x over previous
//
#include <hip/hip_runtime.h>
#include <math.h>

#define NUM_EMB 512
#define EDIM 64
#define BATCH 32
#define HW 4096
#define NROWS (BATCH * HW)        // 131072
#define NQ (NROWS * EDIM)         // 8388608

// LDS layout in floats (total 33536 floats = 134144 B) — R8-proven
#define XOFF 0                    // x_t[c][r]   : c*256 + r   (64 x 256)
#define EOFF 16384                // e_t[c][k]   : c*256 + k   (64 x 256, per pass)
#define T2OFF 32768               // t2s[512]
#define T1OFF 33280               // t1s[256]
#define CBOFF 16384               // combine best  [kt][r] (overlays e_t)
#define CKOFF (16384 + 4096)      // combine bestk [kt][r] (int, overlays e_t)
#define SFLOATS 33536

typedef float f32x4 __attribute__((ext_vector_type(4)));

// numpy pairwise_sum for n=64 contiguous fp32 (tiny prep kernel only).
__device__ __forceinline__ float pairwise8_64(const float* v) {
    float r0 = v[0], r1 = v[1], r2 = v[2], r3 = v[3];
    float r4 = v[4], r5 = v[5], r6 = v[6], r7 = v[7];
#pragma unroll
    for (int i = 8; i < 64; i += 8) {
        r0 = __fadd_rn(r0, v[i + 0]);
        r1 = __fadd_rn(r1, v[i + 1]);
        r2 = __fadd_rn(r2, v[i + 2]);
        r3 = __fadd_rn(r3, v[i + 3]);
        r4 = __fadd_rn(r4, v[i + 4]);
        r5 = __fadd_rn(r5, v[i + 5]);
        r6 = __fadd_rn(r6, v[i + 6]);
        r7 = __fadd_rn(r7, v[i + 7]);
    }
    return __fadd_rn(__fadd_rn(__fadd_rn(r0, r1), __fadd_rn(r2, r3)),
                     __fadd_rn(__fadd_rn(r4, r5), __fadd_rn(r6, r7)));
}

// ws_f layout: [0] = loss sum accumulator, [8..8+511] = t2[k] = ||emb_k||^2
__global__ void vq_prep(const float* __restrict__ emb, float* __restrict__ ws_f) {
    int k = blockIdx.x * blockDim.x + threadIdx.x;
    if (k == 0) ws_f[0] = 0.0f;
    if (k < NUM_EMB) {
        const float* e = emb + k * EDIM;
        float sq[EDIM];
#pragma unroll
        for (int c = 0; c < EDIM; ++c) sq[c] = __fmul_rn(e[c], e[c]);
        ws_f[8 + k] = pairwise8_64(sq);
    }
}

// ---- pipelined asm inner loop machinery ------------------------------------
// READ(SET, c): 4 ds_read_b128 from two base VGPRs with LITERAL byte offsets
// (c*1024 [+512] from bx; c*1024 [+16] from be). Zero per-read address VALU.
#define READ(P, C) \
    asm volatile("ds_read_b128 %0, %1 offset:%2" \
                 : "=v"(P##xa) : "v"(bx), "n"((C) * 1024)); \
    asm volatile("ds_read_b128 %0, %1 offset:%2" \
                 : "=v"(P##xb) : "v"(bx), "n"((C) * 1024 + 512)); \
    asm volatile("ds_read_b128 %0, %1 offset:%2" \
                 : "=v"(P##ea) : "v"(be), "n"((C) * 1024)); \
    asm volatile("ds_read_b128 %0, %1 offset:%2" \
                 : "=v"(P##eb) : "v"(be), "n"((C) * 1024 + 16));

// Counted waits: LDS returns in order (m135) -> lgkmcnt(4) = oldest 4 done.
#define WAIT4 asm volatile("s_waitcnt lgkmcnt(4)"); __builtin_amdgcn_sched_barrier(0);
#define WAIT0 asm volatile("s_waitcnt lgkmcnt(0)"); __builtin_amdgcn_sched_barrier(0);

// Bit-exact R8 FMA body for one c: each acc[i][j] gets ONE fma in its
// ascending-c sequential chain.
#define ROW1(i, xv, P) \
    acc[i][0] = __fmaf_rn(xv, P##ea.x, acc[i][0]); \
    acc[i][1] = __fmaf_rn(xv, P##ea.y, acc[i][1]); \
    acc[i][2] = __fmaf_rn(xv, P##ea.z, acc[i][2]); \
    acc[i][3] = __fmaf_rn(xv, P##ea.w, acc[i][3]); \
    acc[i][4] = __fmaf_rn(xv, P##eb.x, acc[i][4]); \
    acc[i][5] = __fmaf_rn(xv, P##eb.y, acc[i][5]); \
    acc[i][6] = __fmaf_rn(xv, P##eb.z, acc[i][6]); \
    acc[i][7] = __fmaf_rn(xv, P##eb.w, acc[i][7]);
#define FMA64(P) \
    ROW1(0, P##xa.x, P) ROW1(1, P##xa.y, P) ROW1(2, P##xa.z, P) ROW1(3, P##xa.w, P) \
    ROW1(4, P##xb.x, P) ROW1(5, P##xb.y, P) ROW1(6, P##xb.z, P) ROW1(7, P##xb.w, P)

// One pipelined double-step: process c=2m+... with A while B's reads fly.
#define ST(m) \
    READ(B_, 2 * m + 1) WAIT4 FMA64(A_) \
    READ(A_, 2 * m + 2) WAIT4 FMA64(B_)
#define DO31(F) \
  F(0) F(1) F(2) F(3) F(4) F(5) F(6) F(7) F(8) F(9) F(10) F(11) F(12) F(13) \
  F(14) F(15) F(16) F(17) F(18) F(19) F(20) F(21) F(22) F(23) F(24) F(25) \
  F(26) F(27) F(28) F(29) F(30)

// R8 geometry + asm-pipelined inner loop. 512 thr = 32 row-threads x 16
// k-threads; acc[8][8]; conflict-free x (rows rt*4 and 128+rt*4); e reads
// half-wave-uniform (broadcast). Reads pipelined 1 c-iter ahead with counted
// lgkmcnt(4); sched_barrier(0) per wait (rule 18). FMAs are C-level
// __fmaf_rn on asm outputs -> arithmetic identical to R8 (absmax 0.0).
__global__ __launch_bounds__(512, 2) void vq_main(const float* __restrict__ z,
                                                  const float* __restrict__ emb,
                                                  float* __restrict__ out,
                                                  float* __restrict__ ws_f) {
    __shared__ float S[SFLOATS];
    const int tid = threadIdx.x;
    const int rt  = tid & 31;
    const int kt  = tid >> 5;
    const int row0 = rt * 4;
    const int bb  = blockIdx.x;
    const int b   = bb >> 4;
    const int hwb = (bb & 15) << 8;

    const float* zb = z + (size_t)b * (EDIM * HW) + hwb;

    // ---- stage x_t[c][r] (transposed) + t2s ----
    {
        const int r = tid & 255, ch = tid >> 8;
#pragma unroll
        for (int j = 0; j < 32; ++j) {
            const int c = ch * 32 + j;
            S[XOFF + c * 256 + r] = zb[(size_t)c * HW + r];
        }
    }
    S[T2OFF + tid] = ws_f[8 + tid];
    __syncthreads();

    // ---- t1 per row: numpy pairwise-8, ascending c ----
    if (tid < 256) {
        const float* xr = &S[XOFF + tid];
        float q0 = __fmul_rn(xr[0 * 256], xr[0 * 256]);
        float q1 = __fmul_rn(xr[1 * 256], xr[1 * 256]);
        float q2 = __fmul_rn(xr[2 * 256], xr[2 * 256]);
        float q3 = __fmul_rn(xr[3 * 256], xr[3 * 256]);
        float q4 = __fmul_rn(xr[4 * 256], xr[4 * 256]);
        float q5 = __fmul_rn(xr[5 * 256], xr[5 * 256]);
        float q6 = __fmul_rn(xr[6 * 256], xr[6 * 256]);
        float q7 = __fmul_rn(xr[7 * 256], xr[7 * 256]);
#pragma unroll
        for (int m = 1; m < 8; ++m) {
            float v0 = xr[(8 * m + 0) * 256], v1 = xr[(8 * m + 1) * 256];
            float v2 = xr[(8 * m + 2) * 256], v3 = xr[(8 * m + 3) * 256];
            float v4 = xr[(8 * m + 4) * 256], v5 = xr[(8 * m + 5) * 256];
            float v6 = xr[(8 * m + 6) * 256], v7 = xr[(8 * m + 7) * 256];
            q0 = __fadd_rn(q0, __fmul_rn(v0, v0));
            q1 = __fadd_rn(q1, __fmul_rn(v1, v1));
            q2 = __fadd_rn(q2, __fmul_rn(v2, v2));
            q3 = __fadd_rn(q3, __fmul_rn(v3, v3));
            q4 = __fadd_rn(q4, __fmul_rn(v4, v4));
            q5 = __fadd_rn(q5, __fmul_rn(v5, v5));
            q6 = __fadd_rn(q6, __fmul_rn(v6, v6));
            q7 = __fadd_rn(q7, __fmul_rn(v7, v7));
        }
        S[T1OFF + tid] = __fadd_rn(__fadd_rn(__fadd_rn(q0, q1), __fadd_rn(q2, q3)),
                                   __fadd_rn(__fadd_rn(q4, q5), __fadd_rn(q6, q7)));
    }
    __syncthreads();

    float t1r[8];
#pragma unroll
    for (int i = 0; i < 4; ++i) t1r[i] = S[T1OFF + row0 + i];
#pragma unroll
    for (int i = 4; i < 8; ++i) t1r[i] = S[T1OFF + 128 + row0 + (i - 4)];

    float best[8];
    int   bki[8];
#pragma unroll
    for (int i = 0; i < 8; ++i) { best[i] = INFINITY; bki[i] = 0; }

    // ---- two passes over the codebook (256 k each) ----
#pragma unroll 1
    for (int p = 0; p < 2; ++p) {
        // stage e_t[c][k] (transposed); lanes write consecutive k
        {
            const int k = tid & 255, ch = tid >> 8;
            const f32x4* er = (const f32x4*)(emb + (size_t)(p * 256 + k) * EDIM);
#pragma unroll
            for (int j = 0; j < 8; ++j) {
                const f32x4 v = er[ch * 8 + j];
                const int c = ch * 32 + j * 4;
                S[EOFF + (c + 0) * 256 + k] = v.x;
                S[EOFF + (c + 1) * 256 + k] = v.y;
                S[EOFF + (c + 2) * 256 + k] = v.z;
                S[EOFF + (c + 3) * 256 + k] = v.w;
            }
        }
        __syncthreads();

#pragma unroll 1
        for (int blk = 0; blk < 2; ++blk) {
            const int kb = kt * 16 + blk * 8;
            // base addresses (32-bit LDS byte addresses)
            const unsigned bx = (unsigned)(uintptr_t)&S[XOFF + row0];
            const unsigned be = (unsigned)(uintptr_t)&S[EOFF + kb];

            float acc[8][8];
#pragma unroll
            for (int i = 0; i < 8; ++i)
#pragma unroll
                for (int j = 0; j < 8; ++j) acc[i][j] = 0.0f;

            f32x4 A_xa, A_xb, A_ea, A_eb;
            f32x4 B_xa, B_xb, B_ea, B_eb;

            READ(A_, 0)
            DO31(ST)
            READ(B_, 63) WAIT4 FMA64(A_)
            WAIT0 FMA64(B_)

            // finish: d = fl(fl(t1 + t2) - fl(2*p)); in-thread k ascending
#pragma unroll
            for (int j = 0; j < 8; ++j) {
                const int kg = p * 256 + kb + j;
                const float t2k = S[T2OFF + kg];
#pragma unroll
                for (int i = 0; i < 8; ++i) {
                    float d = __fsub_rn(__fadd_rn(t1r[i], t2k),
                                        __fmul_rn(2.0f, acc[i][j]));
                    if (d < best[i]) { best[i] = d; bki[i] = kg; }
                }
            }
        }
        __syncthreads();   // e_t consumed; safe to restage / overlay
    }

    // ---- combine across the 16 k-threads (overlay on e_t region) ----
#pragma unroll
    for (int i = 0; i < 4; ++i) {
        S[CBOFF + kt * 256 + row0 + i] = best[i];
        ((int*)S)[CKOFF + kt * 256 + row0 + i] = bki[i];
    }
#pragma unroll
    for (int i = 4; i < 8; ++i) {
        S[CBOFF + kt * 256 + 128 + row0 + (i - 4)] = best[i];
        ((int*)S)[CKOFF + kt * 256 + 128 + row0 + (i - 4)] = bki[i];
    }
    __syncthreads();

    if (tid < 256) {
        const int row = tid;
        float B = INFINITY;
        int   K = 0;
        // lexicographic (d, k) min == numpy argmin lowest-index tie-break
#pragma unroll
        for (int q = 0; q < 16; ++q) {
            const float bq = S[CBOFF + q * 256 + row];
            const int   kq = ((int*)S)[CKOFF + q * 256 + row];
            if (bq < B || (bq == B && kq < K)) { B = bq; K = kq; }
        }

        // epilogue: qst = fl(x + fl(q - x)), loss partial, idx
        const float* eb = emb + (size_t)K * EDIM;
        const float* xc = &S[XOFF + row];
        float s = 0.0f;
#pragma unroll
        for (int c = 0; c < 64; ++c) {
            const float x = xc[c * 256];
            const float f = __fsub_rn(eb[c], x);
            out[((size_t)b * EDIM + c) * HW + hwb + row] = __fadd_rn(x, f);
            s = __fmaf_rn(f, f, s);
        }
        out[(size_t)NQ + 2 + bb * 256 + row] = (float)K;

#pragma unroll
        for (int off = 32; off > 0; off >>= 1) s += __shfl_down(s, off);
        if ((tid & 63) == 0) atomicAdd(ws_f, s);
    }
}

__global__ void vq_final(const float* __restrict__ ws_f, float* __restrict__ out) {
    float m = ws_f[0] * (1.0f / (float)NQ);   // 2^-23, exact scaling
    out[NQ + 0] = m;
    out[NQ + 1] = m;
}

extern "C" void kernel_launch(void* const* d_in, const int* in_sizes, int n_in,
                              void* d_out, int out_size, void* d_ws, size_t ws_size,
                              hipStream_t stream) {
    const float* z = (const float*)d_in[0];     // [32, 64, 64, 64] fp32
    const float* emb = (const float*)d_in[1];   // [512, 64] fp32
    float* out = (float*)d_out;
    float* ws_f = (float*)d_ws;

    hipLaunchKernelGGL(vq_prep, dim3(1), dim3(512), 0, stream, emb, ws_f);
    hipLaunchKernelGGL(vq_main, dim3(NROWS / 256), dim3(512), 0, stream, z, emb, out, ws_f);
    hipLaunchKernelGGL(vq_final, dim3(1), dim3(1), 0, stream, ws_f, out);
}